// Round 17
// baseline (2289.345 us; speedup 1.0000x reference)
//
#include <hip/hip_runtime.h>

// SimpleLSTM B=256, T=512, I=3, H=512. out = fc(h_T).
// R17 = R16 compute core (known-pass 1.698ms, absmax 2.441e-4) with the
// exchange layer replaced by TAGGED-DATA dataflow:
//  - h stored as u32 = (tag<<16) | fp16(h), tag = step+1 (h_t tagged t+1).
//  - consumers POLL THE DATA: load own fragments, check 16 embedded tags
//    == t+1, retry. Removes drain + flag-publish + separate A-load from
//    the critical path (store visibility IS the tag arrival).
//  - WAR: triple-buffered planes + lazy progress flag (tid0 publishes
//    t+1 after sync1 = all waves' loads done; wave0 polls all 16 >= t-1
//    with 2-step slack -> off the forward path).
//  - final step: one drain + done-flag for the FC epilogue only.
// All polls bounded (R11 lesson). No cache fences (R14 lesson).
// Compute: 16 batch-groups x 16 hidden-blocks (HS=32), 8 waves = K-eighths,
// W f16 in registers, 4-buffer LDS reduction (pad 20), combine fp32.

#define Hh   512
#define Bsz  256
#define Tt   512

#define MB   16
#define HS   32
#define NROW 128
#define NTHR 512
#define NWG  256

typedef float    f32x4 __attribute__((ext_vector_type(4)));
typedef unsigned u32x4 __attribute__((ext_vector_type(4)));
typedef _Float16 f16x8 __attribute__((ext_vector_type(8)));
typedef unsigned long long u64;

#define PLANE_ELE (Bsz * Hh)                     // u32 elements per plane
#define PLANES   3
#define BAR_OFF  (PLANES * PLANE_ELE * 4)        // 1.5 MB planes, then ctrl
#define CTRL_UINTS 8192                          // 16 groups x 512

__device__ __forceinline__ float sigm(float v)  { return 1.0f / (1.0f + __expf(-v)); }
__device__ __forceinline__ float tanhx(float v) { return 2.0f / (1.0f + __expf(-2.0f * v)) - 1.0f; }

__device__ __forceinline__ float h2f(ushort u) {
  return (float)__builtin_bit_cast(_Float16, u);
}
__device__ __forceinline__ ushort f2h(float f) {
  return __builtin_bit_cast(ushort, (_Float16)f);
}

#define GLOAD(dst, base, imm)                                            \
  asm volatile("global_load_dwordx4 %0, %1, off offset:%c2 sc0 sc1"      \
               : "=v"(dst) : "v"(base), "i"(imm))

__global__ void init_ws(unsigned* ctrl) {
  for (int i = threadIdx.x; i < CTRL_UINTS; i += NTHR) ctrl[i] = 0u;
}

__global__ __launch_bounds__(NTHR, 2)
void lstm_kernel(const float* __restrict__ x,   const float* __restrict__ Wih,
                 const float* __restrict__ Whh, const float* __restrict__ bih,
                 const float* __restrict__ bhh, const float* __restrict__ fcw,
                 const float* __restrict__ fcb, float* __restrict__ out,
                 char* __restrict__ ws)
{
  const int tid = threadIdx.x;
  const int wg  = blockIdx.x;
  const int bb  = wg & 15;             // batch group (16 batches)
  const int hb  = wg >> 4;             // hidden block (32 hidden)
  const int j0  = hb * HS;
  const int b0  = bb * MB;

  unsigned* hpl  = (unsigned*)ws;                          // [3][256][512] u32
  unsigned* ctrl = (unsigned*)(ws + BAR_OFF) + bb * 512;   // progress [hb*16], done [256+hb*16]

  __shared__ float gates2[4][NROW][20];    // K-partials (4 bufs), pad 20
  __shared__ float wih_s[NROW][3];
  __shared__ float bsum[NROW];
  __shared__ float xs[MB][3];

  if (tid < NROW) {
    int qq = tid >> 5, jj = tid & 31;
    int grow = qq * Hh + j0 + jj;
    wih_s[tid][0] = Wih[grow * 3 + 0];
    wih_s[tid][1] = Wih[grow * 3 + 1];
    wih_s[tid][2] = Wih[grow * 3 + 2];
    bsum[tid] = bih[grow] + bhh[grow];
  }

  const int l   = tid & 63;
  const int ks  = tid >> 6;            // K-eighth (0..7)
  const int lm  = l & 15;
  const int lk  = l >> 4;              // 0..3

  // ---- W fragments -> registers (single-plane f16), same as R16 ----
  f16x8 wfrag[8][2];
  #pragma unroll
  for (int rb = 0; rb < 8; ++rb) {
    #pragma unroll
    for (int kb = 0; kb < 2; ++kb) {
      int rr = rb * 16 + lm;
      int grow = (rr >> 5) * Hh + j0 + (rr & 31);
      int col = (ks * 2 + kb) * 32 + lk * 8;
      const float* wsrc = Whh + (size_t)grow * Hh + col;
      float4 wa = *(const float4*)(wsrc);
      float4 wb = *(const float4*)(wsrc + 4);
      f16x8 f;
      f[0] = (_Float16)wa.x; f[1] = (_Float16)wa.y;
      f[2] = (_Float16)wa.z; f[3] = (_Float16)wa.w;
      f[4] = (_Float16)wb.x; f[5] = (_Float16)wb.y;
      f[6] = (_Float16)wb.z; f[7] = (_Float16)wb.w;
      wfrag[rb][kb] = f;
    }
  }

  // ---- init h_0 slice in plane 0: u32 = (tag=1)<<16 | fp16(0) ----
  {
    int cb0 = tid >> 5, cj0 = tid & 31;
    size_t o = (size_t)(b0 + cb0) * Hh + j0 + cj0;
    unsigned v0 = 0x00010000u;
    asm volatile("global_store_dword %0, %1, off sc0 sc1" :: "v"(hpl + o), "v"(v0));
  }
  // no drain/publish needed: consumers tag-poll until visible.

  // u32 base index for this lane's fragments
  const size_t aoff = (size_t)(b0 + lm) * Hh + ks * 64 + lk * 8;

  const int cb = tid >> 5;             // combine batch (0..15)
  const int cj = tid & 31;             // combine hidden (0..31)
  float c_state = 0.0f;

  int rd = 0, wr = 1;
  for (int t = 0; t < Tt; ++t) {
    // ---- stage x_t early (off critical path) ----
    if (tid < MB * 3) {
      int b = tid / 3, ii = tid - b * 3;
      xs[b][ii] = x[(size_t)(b0 + b) * (Tt * 3) + t * 3 + ii];
    }

    // ---- wave0: lazy WAR gate (all 16 progress >= t-1, 2-step slack) ----
    if (ks == 0) {
      const unsigned twar = (t >= 1) ? (unsigned)(t - 1) : 0u;
      if (twar > 0) {
        unsigned v = 0xFFFFFFFFu;
        const unsigned* fp = ctrl + (l & 15) * 16;
        int spins = 0;
        for (;;) {
          if (l < 16)
            asm volatile("global_load_dword %0, %1, off sc0 sc1" : "=v"(v) : "v"(fp) : "memory");
          asm volatile("s_waitcnt vmcnt(0)" ::: "memory");
          if (__all((int)(v >= twar))) break;
          if (++spins > (1 << 16)) break;
          __builtin_amdgcn_s_sleep(1);
        }
      }
    }

    // ---- tagged-data poll: load own fragments until all 16 tags == t+1 ----
    const char* pA = (const char*)(hpl + (size_t)rd * PLANE_ELE + aoff);
    const unsigned exp_hi = ((unsigned)(t + 1)) << 16;
    u32x4 D0, D1, D2, D3;
    {
      int spins = 0;
      for (;;) {
        GLOAD(D0, pA, 0);   GLOAD(D1, pA, 16);
        GLOAD(D2, pA, 128); GLOAD(D3, pA, 144);
        asm volatile("s_waitcnt vmcnt(0)" ::: "memory");
        unsigned bad = 0;
        #pragma unroll
        for (int e = 0; e < 4; ++e) {
          bad |= (D0[e] ^ exp_hi) & 0xFFFF0000u;
          bad |= (D1[e] ^ exp_hi) & 0xFFFF0000u;
          bad |= (D2[e] ^ exp_hi) & 0xFFFF0000u;
          bad |= (D3[e] ^ exp_hi) & 0xFFFF0000u;
        }
        if (__all((int)(bad == 0u))) break;
        if (++spins > (1 << 16)) break;
        __builtin_amdgcn_s_sleep(1);
      }
    }
    __builtin_amdgcn_sched_barrier(0);

    // ---- unpack lo16 -> f16 fragments ----
    f16x8 ahk[2];
    {
      ushort tmp0[8], tmp1[8];
      #pragma unroll
      for (int e = 0; e < 4; ++e) {
        tmp0[e]     = (ushort)(D0[e] & 0xFFFFu);
        tmp0[e + 4] = (ushort)(D1[e] & 0xFFFFu);
        tmp1[e]     = (ushort)(D2[e] & 0xFFFFu);
        tmp1[e + 4] = (ushort)(D3[e] & 0xFFFFu);
      }
      ahk[0] = __builtin_bit_cast(f16x8, *(u32x4*)tmp0);
      ahk[1] = __builtin_bit_cast(f16x8, *(u32x4*)tmp1);
    }

    // ---- 8 row-blocks x 2 k-blocks = 16 MFMAs ----
    f32x4 acc[8];
    #pragma unroll
    for (int rb = 0; rb < 8; ++rb) acc[rb] = (f32x4){0.f, 0.f, 0.f, 0.f};
    #pragma unroll
    for (int kb = 0; kb < 2; ++kb) {
      #pragma unroll
      for (int rb = 0; rb < 8; ++rb)
        acc[rb] = __builtin_amdgcn_mfma_f32_16x16x32_f16(ahk[kb], wfrag[rb][kb], acc[rb], 0, 0, 0);
    }

    // ---- 4-buffer K-partial reduction in LDS ----
    if (ks < 4) {
      #pragma unroll
      for (int rb = 0; rb < 8; ++rb)
        #pragma unroll
        for (int r = 0; r < 4; ++r)
          gates2[ks][rb * 16 + lm][lk * 4 + r] = acc[rb][r];
    }
    __syncthreads();
    // progress publish: all waves' loads complete at this point
    if (tid == 0) {
      unsigned pv = (unsigned)(t + 1);
      asm volatile("global_store_dword %0, %1, off sc0 sc1"
                   :: "v"(ctrl + hb * 16), "v"(pv) : "memory");
    }
    if (ks >= 4) {
      #pragma unroll
      for (int rb = 0; rb < 8; ++rb)
        #pragma unroll
        for (int r = 0; r < 4; ++r)
          gates2[ks - 4][rb * 16 + lm][lk * 4 + r] += acc[rb][r];
    }
    __syncthreads();

    // ---- gate combine + tagged u32 h store into plane wr ----
    {
      float xv0 = xs[cb][0], xv1 = xs[cb][1], xv2 = xs[cb][2];
      float pre[4];
      #pragma unroll
      for (int qq = 0; qq < 4; ++qq) {
        int rrq = qq * 32 + cj;
        pre[qq] = gates2[0][rrq][cb] + gates2[1][rrq][cb]
                + gates2[2][rrq][cb] + gates2[3][rrq][cb] + bsum[rrq]
                + xv0 * wih_s[rrq][0] + xv1 * wih_s[rrq][1] + xv2 * wih_s[rrq][2];
      }
      float ig = sigm(pre[0]), fg = sigm(pre[1]);
      float gg = tanhx(pre[2]), og = sigm(pre[3]);
      c_state = fg * c_state + ig * gg;
      float hv = og * tanhx(c_state);
      unsigned uw = ((unsigned)(t + 2) << 16) | (unsigned)f2h(hv);
      size_t ho = (size_t)wr * PLANE_ELE + (size_t)(b0 + cb) * Hh + j0 + cj;
      asm volatile("global_store_dword %0, %1, off sc0 sc1" :: "v"(hpl + ho), "v"(uw));
    }
    // fire-and-forget: no drain, no flag. Tags carry visibility.

    rd = wr;
    wr = (wr == 2) ? 0 : wr + 1;
  }

  // ---- final: drain h_T stores, publish done flag ----
  asm volatile("s_waitcnt vmcnt(0)" ::: "memory");
  __syncthreads();
  if (tid == 0) {
    unsigned dv = 1u;
    asm volatile("global_store_dword %0, %1, off sc0 sc1"
                 :: "v"(ctrl + 256 + hb * 16), "v"(dv) : "memory");
  }

  // ---- epilogue: hb==0 wgs wait for all done flags, then FC ----
  if (hb == 0) {
    if (tid < 64) {
      unsigned v = 0xFFFFFFFFu;
      const unsigned* fp = ctrl + 256 + (l & 15) * 16;
      int spins = 0;
      for (;;) {
        if (l < 16)
          asm volatile("global_load_dword %0, %1, off sc0 sc1" : "=v"(v) : "v"(fp) : "memory");
        asm volatile("s_waitcnt vmcnt(0)" ::: "memory");
        if (__all((int)(v >= 1u))) break;
        if (++spins > (1 << 16)) break;
        __builtin_amdgcn_s_sleep(1);
      }
    }
    __syncthreads();

    const u64* Hf = (const u64*)(hpl + (size_t)rd * PLANE_ELE);
    int b = tid >> 5, lj = tid & 31;
    float p = 0.0f;
    for (int jd = lj; jd < Hh / 2; jd += 32) {
      size_t o = (size_t)(b0 + b) * (Hh / 2) + jd;
      u64 uh = __hip_atomic_load(Hf + o, __ATOMIC_RELAXED, __HIP_MEMORY_SCOPE_AGENT);
      p += h2f((ushort)(uh & 0xFFFFu)) * fcw[2 * jd];
      p += h2f((ushort)((uh >> 32) & 0xFFFFu)) * fcw[2 * jd + 1];
    }
    __syncthreads();
    ((float*)gates2)[tid] = p;
    __syncthreads();
    if (lj == 0) {
      float s = 0.0f;
      #pragma unroll
      for (int r = 0; r < 32; ++r) s += ((float*)gates2)[(b << 5) + r];
      out[b0 + b] = s + fcb[0];
    }
  }
}

extern "C" void kernel_launch(void* const* d_in, const int* in_sizes, int n_in,
                              void* d_out, int out_size, void* d_ws, size_t ws_size,
                              hipStream_t stream) {
  const float* x   = (const float*)d_in[0];
  const float* Wih = (const float*)d_in[1];
  const float* Whh = (const float*)d_in[2];
  const float* bih = (const float*)d_in[3];
  const float* bhh = (const float*)d_in[4];
  const float* fcw = (const float*)d_in[5];
  const float* fcb = (const float*)d_in[6];
  float* out = (float*)d_out;
  char*  ws  = (char*)d_ws;

  hipLaunchKernelGGL(init_ws, dim3(1), dim3(NTHR), 0, stream,
                     (unsigned*)(ws + BAR_OFF));
  hipLaunchKernelGGL(lstm_kernel, dim3(NWG), dim3(NTHR), 0, stream,
                     x, Wih, Whh, bih, bhh, fcw, fcb, out, ws);
}

// Round 19
// 1528.112 us; speedup vs baseline: 1.4982x; 1.4982x over previous
//
#include <hip/hip_runtime.h>

// SimpleLSTM B=256, T=512, I=3, H=512. out = fc(h_T).
// R19 = R16 (known-pass 1.698ms, absmax 2.441e-4) + two LDS fixes:
//  1. 8-buffer single-sync reduction: each wave writes gates8[ks]; ONE
//     __syncthreads; combine sums all 8 buffers. Removes the 2nd barrier
//     and the serialized RMW pass (waves 4-7) from the per-step chain.
//     WAR ordering preserved: stores follow the single barrier, which
//     wave0 reaches only after its WAR gate.
//  2. Row pad 17 -> 21 (coprime with 32 banks): write pattern 20*lm+4*lk
//     was 4-way conflicted; stride 21 gives <=2-way (free). R16 counter:
//     1.007e8 conflicts.
// Everything else verbatim R16: 16 batch groups (MB=16) x 16 hidden blocks
// (HS=32), 8 waves = K-eighths, W f16 single-plane in registers, R15
// dataflow protocol (triple-buffered fp16 h planes at LLC sc0sc1,
// 2-producer gates, wave0 merged WAR gate, publish t+2, no exit barrier),
// no cache fences (R14 lesson), 1 wg/CU.

#define Hh   512
#define Bsz  256
#define Tt   512

#define MB   16     // batches per group
#define HS   32     // hidden per wg
#define NROW 128    // gate rows per wg
#define NTHR 512
#define NWG  256
#define GP   21     // gates8 row pad (floats), coprime with 32

typedef float    f32x4 __attribute__((ext_vector_type(4)));
typedef _Float16 f16x8 __attribute__((ext_vector_type(8)));
typedef unsigned long long u64;

#define PLANE_ELE (Bsz * Hh)
#define PLANES   3
#define BAR_OFF  (PLANES * PLANE_ELE * 2)    // 768 KB
#define CTRL_UINTS 4096                      // 16 groups x 16 flags x 16-uint stride

__device__ __forceinline__ float sigm(float v)  { return 1.0f / (1.0f + __expf(-v)); }
__device__ __forceinline__ float tanhx(float v) { return 2.0f / (1.0f + __expf(-2.0f * v)) - 1.0f; }

__device__ __forceinline__ float h2f(ushort u) {
  return (float)__builtin_bit_cast(_Float16, u);
}
__device__ __forceinline__ ushort f2h(float f) {
  return __builtin_bit_cast(ushort, (_Float16)f);
}

#define GLOAD(dst, base, imm)                                            \
  asm volatile("global_load_dwordx4 %0, %1, off offset:%c2 sc0 sc1"      \
               : "=v"(dst) : "v"(base), "i"(imm))

__global__ void init_ws(unsigned* ctrl) {
  for (int i = threadIdx.x; i < CTRL_UINTS; i += NTHR) ctrl[i] = 0u;
}

__global__ __launch_bounds__(NTHR, 2)
void lstm_kernel(const float* __restrict__ x,   const float* __restrict__ Wih,
                 const float* __restrict__ Whh, const float* __restrict__ bih,
                 const float* __restrict__ bhh, const float* __restrict__ fcw,
                 const float* __restrict__ fcb, float* __restrict__ out,
                 char* __restrict__ ws)
{
  const int tid = threadIdx.x;
  const int wg  = blockIdx.x;
  const int bb  = wg & 15;             // batch group (16 batches)
  const int hb  = wg >> 4;             // hidden block (32 hidden)
  const int j0  = hb * HS;
  const int b0  = bb * MB;

  ushort*   hpl   = (ushort*)ws;                           // [3][256][512] f16
  unsigned* flags = (unsigned*)(ws + BAR_OFF) + bb * 256;  // flag(hb) at [hb*16]

  __shared__ float gates8[8][NROW][GP];    // per-wave K-partials, ~86 KB
  __shared__ float wih_s[NROW][3];
  __shared__ float bsum[NROW];
  __shared__ float xs[MB][3];

  if (tid < NROW) {
    int qq = tid >> 5, jj = tid & 31;
    int grow = qq * Hh + j0 + jj;
    wih_s[tid][0] = Wih[grow * 3 + 0];
    wih_s[tid][1] = Wih[grow * 3 + 1];
    wih_s[tid][2] = Wih[grow * 3 + 2];
    bsum[tid] = bih[grow] + bhh[grow];
  }

  const int l   = tid & 63;
  const int ks  = tid >> 6;            // K-eighth (0..7), 64 k each
  const int lm  = l & 15;
  const int lk  = l >> 4;              // 0..3

  // ---- W fragments -> registers (single-plane f16), verbatim R16 ----
  f16x8 wfrag[8][2];
  #pragma unroll
  for (int rb = 0; rb < 8; ++rb) {
    #pragma unroll
    for (int kb = 0; kb < 2; ++kb) {
      int rr = rb * 16 + lm;
      int grow = (rr >> 5) * Hh + j0 + (rr & 31);
      int col = (ks * 2 + kb) * 32 + lk * 8;
      const float* wsrc = Whh + (size_t)grow * Hh + col;
      float4 wa = *(const float4*)(wsrc);
      float4 wb = *(const float4*)(wsrc + 4);
      f16x8 f;
      f[0] = (_Float16)wa.x; f[1] = (_Float16)wa.y;
      f[2] = (_Float16)wa.z; f[3] = (_Float16)wa.w;
      f[4] = (_Float16)wb.x; f[5] = (_Float16)wb.y;
      f[6] = (_Float16)wb.z; f[7] = (_Float16)wb.w;
      wfrag[rb][kb] = f;
    }
  }

  // ---- zero h_0 slice in plane 0, publish flag = 1 ----
  {
    int cb0 = tid >> 5, cj0 = tid & 31;
    size_t o = (size_t)(b0 + cb0) * Hh + j0 + cj0;
    __hip_atomic_store(&hpl[o], (ushort)0, __ATOMIC_RELAXED, __HIP_MEMORY_SCOPE_AGENT);
  }
  asm volatile("s_waitcnt vmcnt(0)" ::: "memory");
  __syncthreads();
  if (tid == 0) {
    unsigned fv = 1u;
    asm volatile("global_store_dword %0, %1, off sc0 sc1"
                 :: "v"(flags + hb * 16), "v"(fv) : "memory");
  }

  const size_t aoff = (size_t)(b0 + lm) * Hh + ks * 64 + lk * 8;

  const int cb = tid >> 5;             // combine batch (0..15)
  const int cj = tid & 31;             // combine hidden (0..31)
  float c_state = 0.0f;

  int rd = 0, wr = 1;
  for (int t = 0; t < Tt; ++t) {
    // ---- gates (R15/R16-verified): wave0 merged WAR + own producers;
    //      other waves: own 2 producers (hb = ks*2, ks*2+1) >= t+1 ----
    {
      const unsigned tq = (unsigned)(t + 1);
      const unsigned tw = (unsigned)t;
      if (ks == 0) {
        unsigned v = 0xFFFFFFFFu;
        const unsigned* fp = flags + (l & 15) * 16;
        for (;;) {
          if (l < 16)
            asm volatile("global_load_dword %0, %1, off sc0 sc1" : "=v"(v) : "v"(fp) : "memory");
          asm volatile("s_waitcnt vmcnt(0)" ::: "memory");
          unsigned need = ((l & 15) < 2) ? tq : tw;
          if (__all((int)(v >= need))) break;
          __builtin_amdgcn_s_sleep(2);
        }
      } else {
        unsigned v = 0xFFFFFFFFu;
        const unsigned* fp = flags + (ks * 2 + (l & 1)) * 16;
        for (;;) {
          if (l < 2)
            asm volatile("global_load_dword %0, %1, off sc0 sc1" : "=v"(v) : "v"(fp) : "memory");
          asm volatile("s_waitcnt vmcnt(0)" ::: "memory");
          if (__all((int)(v >= tq))) break;
          __builtin_amdgcn_s_sleep(2);
        }
      }
    }

    if (tid < MB * 3) {
      int b = tid / 3, ii = tid - b * 3;
      xs[b][ii] = x[(size_t)(b0 + b) * (Tt * 3) + t * 3 + ii];
    }

    // ---- 2 pipelined A loads (own K-eighth of h_t) ----
    const char* pH = (const char*)(hpl + (size_t)rd * PLANE_ELE + aoff);
    f32x4 AH[2];
    GLOAD(AH[0], pH, 0);  GLOAD(AH[1], pH, 64);
    asm volatile("s_waitcnt vmcnt(0)" ::: "memory");
    __builtin_amdgcn_sched_barrier(0);

    // ---- 8 row-blocks x 2 k-blocks = 16 MFMAs ----
    f32x4 acc[8];
    #pragma unroll
    for (int rb = 0; rb < 8; ++rb) acc[rb] = (f32x4){0.f, 0.f, 0.f, 0.f};
    #pragma unroll
    for (int kb = 0; kb < 2; ++kb) {
      f16x8 ah = __builtin_bit_cast(f16x8, AH[kb]);
      #pragma unroll
      for (int rb = 0; rb < 8; ++rb)
        acc[rb] = __builtin_amdgcn_mfma_f32_16x16x32_f16(ah, wfrag[rb][kb], acc[rb], 0, 0, 0);
    }

    // ---- single-sync 8-buffer K-partial reduction ----
    // C mapping: batch = lk*4 + r, gate row = rb*16 + lm.
    #pragma unroll
    for (int rb = 0; rb < 8; ++rb)
      #pragma unroll
      for (int r = 0; r < 4; ++r)
        gates8[ks][rb * 16 + lm][lk * 4 + r] = acc[rb][r];
    __syncthreads();   // single barrier; also orders wave0's WAR gate before stores

    // ---- gate combine (sum 8 buffers) + direct fp16 h store ----
    {
      float xv0 = xs[cb][0], xv1 = xs[cb][1], xv2 = xs[cb][2];
      float pre[4];
      #pragma unroll
      for (int qq = 0; qq < 4; ++qq) {
        int rrq = qq * 32 + cj;
        float s = bsum[rrq]
                + xv0 * wih_s[rrq][0] + xv1 * wih_s[rrq][1] + xv2 * wih_s[rrq][2];
        #pragma unroll
        for (int k8 = 0; k8 < 8; ++k8)
          s += gates8[k8][rrq][cb];
        pre[qq] = s;
      }
      float ig = sigm(pre[0]), fg = sigm(pre[1]);
      float gg = tanhx(pre[2]), og = sigm(pre[3]);
      c_state = fg * c_state + ig * gg;
      float hv = og * tanhx(c_state);
      unsigned uhw = f2h(hv);
      size_t ho = (size_t)wr * PLANE_ELE + (size_t)(b0 + cb) * Hh + j0 + cj;
      asm volatile("global_store_short %0, %1, off sc0 sc1" :: "v"(hpl + ho), "v"(uhw));
    }

    // ---- end of step: drain own stores, converge, publish flag ----
    asm volatile("s_waitcnt vmcnt(0)" ::: "memory");
    __syncthreads();
    if (tid == 0) {
      unsigned fv = (unsigned)(t + 2);
      asm volatile("global_store_dword %0, %1, off sc0 sc1"
                   :: "v"(flags + hb * 16), "v"(fv) : "memory");
    }

    rd = wr;
    wr = (wr == 2) ? 0 : wr + 1;
  }

  // ---- epilogue: hb==0 wgs wait for all final h, then FC (16 batches) ----
  if (hb == 0) {
    if (tid < 64) {
      unsigned v = 0xFFFFFFFFu;
      const unsigned* fp = flags + (l & 15) * 16;
      const unsigned tgt = (unsigned)(Tt + 1);
      for (;;) {
        if (l < 16)
          asm volatile("global_load_dword %0, %1, off sc0 sc1" : "=v"(v) : "v"(fp) : "memory");
        asm volatile("s_waitcnt vmcnt(0)" ::: "memory");
        if (__all((int)(v >= tgt))) break;
        __builtin_amdgcn_s_sleep(2);
      }
    }
    __syncthreads();

    const u64* Hf = (const u64*)(hpl + (size_t)rd * PLANE_ELE);
    int b = tid >> 5, lj = tid & 31;
    float p = 0.0f;
    for (int jq = lj; jq < Hh / 4; jq += 32) {
      size_t o = (size_t)(b0 + b) * (Hh / 4) + jq;
      u64 uh = __hip_atomic_load(Hf + o, __ATOMIC_RELAXED, __HIP_MEMORY_SCOPE_AGENT);
      #pragma unroll
      for (int e = 0; e < 4; ++e)
        p += h2f((ushort)(uh >> (16 * e))) * fcw[4 * jq + e];
    }
    __syncthreads();
    ((float*)gates8)[tid] = p;
    __syncthreads();
    if (lj == 0) {
      float s = 0.0f;
      #pragma unroll
      for (int r = 0; r < 32; ++r) s += ((float*)gates8)[(b << 5) + r];
      out[b0 + b] = s + fcb[0];
    }
  }
}

extern "C" void kernel_launch(void* const* d_in, const int* in_sizes, int n_in,
                              void* d_out, int out_size, void* d_ws, size_t ws_size,
                              hipStream_t stream) {
  const float* x   = (const float*)d_in[0];
  const float* Wih = (const float*)d_in[1];
  const float* Whh = (const float*)d_in[2];
  const float* bih = (const float*)d_in[3];
  const float* bhh = (const float*)d_in[4];
  const float* fcw = (const float*)d_in[5];
  const float* fcb = (const float*)d_in[6];
  float* out = (float*)d_out;
  char*  ws  = (char*)d_ws;

  hipLaunchKernelGGL(init_ws, dim3(1), dim3(NTHR), 0, stream,
                     (unsigned*)(ws + BAR_OFF));
  hipLaunchKernelGGL(lstm_kernel, dim3(NWG), dim3(NTHR), 0, stream,
                     x, Wih, Whh, bih, bhh, fcw, fcb, out, ws);
}

// Round 20
// 1527.291 us; speedup vs baseline: 1.4990x; 1.0005x over previous
//
#include <hip/hip_runtime.h>

// SimpleLSTM B=256, T=512, I=3, H=512. out = fc(h_T).
// R20 = R19 (known-pass 1.528ms, absmax 2.441e-4) + three micro-opts:
//  1. xs staged BEFORE the gate poll (independent of flags; prior-step xs
//     reads ordered by the end-of-step barrier) -> overlaps HBM read w/ poll.
//  2. wave0 WAR gate moved AFTER MFMA (before the single barrier): off the
//     pre-load serial path; ordering unchanged (barrier precedes stores).
//  3. poll pacing s_sleep(2) -> s_sleep(0) (flags on 256 distinct lines).
// Everything else verbatim R19: 16 bgroups (MB=16) x 16 hblocks (HS=32),
// 8 waves = K-eighths, W f16 in registers, 8-buffer single-sync reduction
// (pad 21), R15 dataflow protocol (3 fp16 planes at LLC sc0sc1, 2-producer
// gates, WAR slack 2, publish t+2, bounded-free polls, no cache fences).

#define Hh   512
#define Bsz  256
#define Tt   512

#define MB   16
#define HS   32
#define NROW 128
#define NTHR 512
#define NWG  256
#define GP   21

typedef float    f32x4 __attribute__((ext_vector_type(4)));
typedef _Float16 f16x8 __attribute__((ext_vector_type(8)));
typedef unsigned long long u64;

#define PLANE_ELE (Bsz * Hh)
#define PLANES   3
#define BAR_OFF  (PLANES * PLANE_ELE * 2)
#define CTRL_UINTS 4096

__device__ __forceinline__ float sigm(float v)  { return 1.0f / (1.0f + __expf(-v)); }
__device__ __forceinline__ float tanhx(float v) { return 2.0f / (1.0f + __expf(-2.0f * v)) - 1.0f; }

__device__ __forceinline__ float h2f(ushort u) {
  return (float)__builtin_bit_cast(_Float16, u);
}
__device__ __forceinline__ ushort f2h(float f) {
  return __builtin_bit_cast(ushort, (_Float16)f);
}

#define GLOAD(dst, base, imm)                                            \
  asm volatile("global_load_dwordx4 %0, %1, off offset:%c2 sc0 sc1"      \
               : "=v"(dst) : "v"(base), "i"(imm))

__global__ void init_ws(unsigned* ctrl) {
  for (int i = threadIdx.x; i < CTRL_UINTS; i += NTHR) ctrl[i] = 0u;
}

__global__ __launch_bounds__(NTHR, 2)
void lstm_kernel(const float* __restrict__ x,   const float* __restrict__ Wih,
                 const float* __restrict__ Whh, const float* __restrict__ bih,
                 const float* __restrict__ bhh, const float* __restrict__ fcw,
                 const float* __restrict__ fcb, float* __restrict__ out,
                 char* __restrict__ ws)
{
  const int tid = threadIdx.x;
  const int wg  = blockIdx.x;
  const int bb  = wg & 15;
  const int hb  = wg >> 4;
  const int j0  = hb * HS;
  const int b0  = bb * MB;

  ushort*   hpl   = (ushort*)ws;
  unsigned* flags = (unsigned*)(ws + BAR_OFF) + bb * 256;

  __shared__ float gates8[8][NROW][GP];
  __shared__ float wih_s[NROW][3];
  __shared__ float bsum[NROW];
  __shared__ float xs[MB][3];

  if (tid < NROW) {
    int qq = tid >> 5, jj = tid & 31;
    int grow = qq * Hh + j0 + jj;
    wih_s[tid][0] = Wih[grow * 3 + 0];
    wih_s[tid][1] = Wih[grow * 3 + 1];
    wih_s[tid][2] = Wih[grow * 3 + 2];
    bsum[tid] = bih[grow] + bhh[grow];
  }

  const int l   = tid & 63;
  const int ks  = tid >> 6;
  const int lm  = l & 15;
  const int lk  = l >> 4;

  f16x8 wfrag[8][2];
  #pragma unroll
  for (int rb = 0; rb < 8; ++rb) {
    #pragma unroll
    for (int kb = 0; kb < 2; ++kb) {
      int rr = rb * 16 + lm;
      int grow = (rr >> 5) * Hh + j0 + (rr & 31);
      int col = (ks * 2 + kb) * 32 + lk * 8;
      const float* wsrc = Whh + (size_t)grow * Hh + col;
      float4 wa = *(const float4*)(wsrc);
      float4 wb = *(const float4*)(wsrc + 4);
      f16x8 f;
      f[0] = (_Float16)wa.x; f[1] = (_Float16)wa.y;
      f[2] = (_Float16)wa.z; f[3] = (_Float16)wa.w;
      f[4] = (_Float16)wb.x; f[5] = (_Float16)wb.y;
      f[6] = (_Float16)wb.z; f[7] = (_Float16)wb.w;
      wfrag[rb][kb] = f;
    }
  }

  {
    int cb0 = tid >> 5, cj0 = tid & 31;
    size_t o = (size_t)(b0 + cb0) * Hh + j0 + cj0;
    __hip_atomic_store(&hpl[o], (ushort)0, __ATOMIC_RELAXED, __HIP_MEMORY_SCOPE_AGENT);
  }
  asm volatile("s_waitcnt vmcnt(0)" ::: "memory");
  __syncthreads();
  if (tid == 0) {
    unsigned fv = 1u;
    asm volatile("global_store_dword %0, %1, off sc0 sc1"
                 :: "v"(flags + hb * 16), "v"(fv) : "memory");
  }

  const size_t aoff = (size_t)(b0 + lm) * Hh + ks * 64 + lk * 8;

  const int cb = tid >> 5;
  const int cj = tid & 31;
  float c_state = 0.0f;

  int rd = 0, wr = 1;
  for (int t = 0; t < Tt; ++t) {
    // ---- stage x_t FIRST (independent of flags; ordered vs prior combine
    //      by the end-of-step barrier) ----
    if (tid < MB * 3) {
      int b = tid / 3, ii = tid - b * 3;
      xs[b][ii] = x[(size_t)(b0 + b) * (Tt * 3) + t * 3 + ii];
    }

    // ---- producer gate (all waves, incl. wave0): own 2 producers >= t+1 ----
    {
      const unsigned tq = (unsigned)(t + 1);
      unsigned v = 0xFFFFFFFFu;
      const unsigned* fp = flags + (ks * 2 + (l & 1)) * 16;
      for (;;) {
        if (l < 2)
          asm volatile("global_load_dword %0, %1, off sc0 sc1" : "=v"(v) : "v"(fp) : "memory");
        asm volatile("s_waitcnt vmcnt(0)" ::: "memory");
        if (__all((int)(v >= tq))) break;
        __builtin_amdgcn_s_sleep(0);
      }
    }

    // ---- 2 pipelined A loads (own K-eighth of h_t) ----
    const char* pH = (const char*)(hpl + (size_t)rd * PLANE_ELE + aoff);
    f32x4 AH[2];
    GLOAD(AH[0], pH, 0);  GLOAD(AH[1], pH, 64);
    asm volatile("s_waitcnt vmcnt(0)" ::: "memory");
    __builtin_amdgcn_sched_barrier(0);

    // ---- 8 row-blocks x 2 k-blocks = 16 MFMAs ----
    f32x4 acc[8];
    #pragma unroll
    for (int rb = 0; rb < 8; ++rb) acc[rb] = (f32x4){0.f, 0.f, 0.f, 0.f};
    #pragma unroll
    for (int kb = 0; kb < 2; ++kb) {
      f16x8 ah = __builtin_bit_cast(f16x8, AH[kb]);
      #pragma unroll
      for (int rb = 0; rb < 8; ++rb)
        acc[rb] = __builtin_amdgcn_mfma_f32_16x16x32_f16(ah, wfrag[rb][kb], acc[rb], 0, 0, 0);
    }

    // ---- wave0 WAR gate (all 16 flags >= t, slack 2), now AFTER MFMA ----
    if (ks == 0 && t >= 1) {
      const unsigned tw = (unsigned)t;
      unsigned v = 0xFFFFFFFFu;
      const unsigned* fp = flags + (l & 15) * 16;
      for (;;) {
        if (l < 16)
          asm volatile("global_load_dword %0, %1, off sc0 sc1" : "=v"(v) : "v"(fp) : "memory");
        asm volatile("s_waitcnt vmcnt(0)" ::: "memory");
        if (__all((int)(v >= tw))) break;
        __builtin_amdgcn_s_sleep(0);
      }
    }

    // ---- single-sync 8-buffer K-partial reduction ----
    #pragma unroll
    for (int rb = 0; rb < 8; ++rb)
      #pragma unroll
      for (int r = 0; r < 4; ++r)
        gates8[ks][rb * 16 + lm][lk * 4 + r] = acc[rb][r];
    __syncthreads();   // orders WAR gate + all partials before stores

    // ---- gate combine (sum 8 buffers) + direct fp16 h store ----
    {
      float xv0 = xs[cb][0], xv1 = xs[cb][1], xv2 = xs[cb][2];
      float pre[4];
      #pragma unroll
      for (int qq = 0; qq < 4; ++qq) {
        int rrq = qq * 32 + cj;
        float s = bsum[rrq]
                + xv0 * wih_s[rrq][0] + xv1 * wih_s[rrq][1] + xv2 * wih_s[rrq][2];
        #pragma unroll
        for (int k8 = 0; k8 < 8; ++k8)
          s += gates8[k8][rrq][cb];
        pre[qq] = s;
      }
      float ig = sigm(pre[0]), fg = sigm(pre[1]);
      float gg = tanhx(pre[2]), og = sigm(pre[3]);
      c_state = fg * c_state + ig * gg;
      float hv = og * tanhx(c_state);
      unsigned uhw = f2h(hv);
      size_t ho = (size_t)wr * PLANE_ELE + (size_t)(b0 + cb) * Hh + j0 + cj;
      asm volatile("global_store_short %0, %1, off sc0 sc1" :: "v"(hpl + ho), "v"(uhw));
    }

    // ---- end of step: drain own stores, converge, publish flag ----
    asm volatile("s_waitcnt vmcnt(0)" ::: "memory");
    __syncthreads();
    if (tid == 0) {
      unsigned fv = (unsigned)(t + 2);
      asm volatile("global_store_dword %0, %1, off sc0 sc1"
                   :: "v"(flags + hb * 16), "v"(fv) : "memory");
    }

    rd = wr;
    wr = (wr == 2) ? 0 : wr + 1;
  }

  // ---- epilogue: hb==0 wgs wait for all final h, then FC ----
  if (hb == 0) {
    if (tid < 64) {
      unsigned v = 0xFFFFFFFFu;
      const unsigned* fp = flags + (l & 15) * 16;
      const unsigned tgt = (unsigned)(Tt + 1);
      for (;;) {
        if (l < 16)
          asm volatile("global_load_dword %0, %1, off sc0 sc1" : "=v"(v) : "v"(fp) : "memory");
        asm volatile("s_waitcnt vmcnt(0)" ::: "memory");
        if (__all((int)(v >= tgt))) break;
        __builtin_amdgcn_s_sleep(1);
      }
    }
    __syncthreads();

    const u64* Hf = (const u64*)(hpl + (size_t)rd * PLANE_ELE);
    int b = tid >> 5, lj = tid & 31;
    float p = 0.0f;
    for (int jq = lj; jq < Hh / 4; jq += 32) {
      size_t o = (size_t)(b0 + b) * (Hh / 4) + jq;
      u64 uh = __hip_atomic_load(Hf + o, __ATOMIC_RELAXED, __HIP_MEMORY_SCOPE_AGENT);
      #pragma unroll
      for (int e = 0; e < 4; ++e)
        p += h2f((ushort)(uh >> (16 * e))) * fcw[4 * jq + e];
    }
    __syncthreads();
    ((float*)gates8)[tid] = p;
    __syncthreads();
    if (lj == 0) {
      float s = 0.0f;
      #pragma unroll
      for (int r = 0; r < 32; ++r) s += ((float*)gates8)[(b << 5) + r];
      out[b0 + b] = s + fcb[0];
    }
  }
}

extern "C" void kernel_launch(void* const* d_in, const int* in_sizes, int n_in,
                              void* d_out, int out_size, void* d_ws, size_t ws_size,
                              hipStream_t stream) {
  const float* x   = (const float*)d_in[0];
  const float* Wih = (const float*)d_in[1];
  const float* Whh = (const float*)d_in[2];
  const float* bih = (const float*)d_in[3];
  const float* bhh = (const float*)d_in[4];
  const float* fcw = (const float*)d_in[5];
  const float* fcb = (const float*)d_in[6];
  float* out = (float*)d_out;
  char*  ws  = (char*)d_ws;

  hipLaunchKernelGGL(init_ws, dim3(1), dim3(NTHR), 0, stream,
                     (unsigned*)(ws + BAR_OFF));
  hipLaunchKernelGGL(lstm_kernel, dim3(NWG), dim3(NTHR), 0, stream,
                     x, Wih, Whh, bih, bhh, fcw, fcb, out, ws);
}